// Round 22
// baseline (197.247 us; speedup 1.0000x reference)
//
#include <hip/hip_runtime.h>

typedef unsigned short u16;
typedef __attribute__((ext_vector_type(8))) short short8;    // 8 x 16-bit payload
typedef __attribute__((ext_vector_type(4))) short s16x4;
typedef __attribute__((ext_vector_type(8))) _Float16 half8;  // MFMA f16 A/B frag
typedef __attribute__((ext_vector_type(4))) float f32x4;
typedef __attribute__((ext_vector_type(16))) float f32x16;
typedef __attribute__((ext_vector_type(4))) unsigned int u32x4;

#define DEVI static __device__ __forceinline__

static constexpr int B_ = 4, N_ = 2048, C_ = 1024, H_ = 16, D_ = 64;
static constexpr int M_ = B_ * N_;   // 8192
static constexpr int C3 = 3072;

DEVI u16 f2h(float f) {
  _Float16 h = (_Float16)f;          // v_cvt_f16_f32, RTN
  return __builtin_bit_cast(u16, h);
}

DEVI unsigned pk2h(float lo, float hi) {  // pack 2 f32 -> 2 f16 (lo in [15:0])
  return __builtin_bit_cast(unsigned, __builtin_amdgcn_cvt_pkrtz(lo, hi));
}

DEVI void gload_lds16(const void* g, void* lds) {
  __builtin_amdgcn_global_load_lds(
      (const __attribute__((address_space(1))) unsigned int*)g,
      (__attribute__((address_space(3))) unsigned int*)lds, 16, 0, 0);
}

// All three f32->f16 casts in one launch (1572864 = 6144*256 chunks of 8).
__global__ __launch_bounds__(256) void f32_to_f16_all(const float* __restrict__ x,
                                                      const float* __restrict__ wq,
                                                      const float* __restrict__ wp,
                                                      u16* __restrict__ x16,
                                                      u16* __restrict__ wq16,
                                                      u16* __restrict__ wp16) {
  int idx = blockIdx.x * 256 + threadIdx.x;
  const float* s;
  u16* d;
  int base;
  if (idx < 1048576) {
    s = x; d = x16; base = idx;
  } else if (idx < 1048576 + 393216) {
    s = wq; d = wq16; base = idx - 1048576;
  } else {
    s = wp; d = wp16; base = idx - 1441792;
  }
  const float* sp = s + (size_t)base * 8;
  f32x4 f0 = *(const f32x4*)sp;
  f32x4 f1 = *(const f32x4*)(sp + 4);
  short8 o;
#pragma unroll
  for (int j = 0; j < 8; ++j) o[j] = (short)f2h(j < 4 ? f0[j] : f1[j - 4]);
  *(short8*)(d + (size_t)base * 8) = o;
}

// QKV GEMM, round 22: 128x128 tile, BK=32, 4 waves (r5/r17 validated body +
// swizzle), with a 3-BUFFER ROTATION and COUNTED vmcnt(4) (T4): tile t
// computes from buf[t%3] while tile t+2 stages into buf[(t+2)%3]; the per-iter
// wait covers ONLY tile t+1's loads (issued a full iteration earlier), so no
// just-issued prefetch is ever drained (r19's failure mode) and the pipe stays
// 2 tiles deep. Race-safe: buf[(t+3)%3]=buf[t%3] is rewritten one barrier
// after its last read; each wave's own vmcnt covers its disjoint quarter of
// the buffer. LDS 48KB -> 3 blocks/CU. Fused LDS-transposed epilogue (r21):
// SH (34KB) aliases staging after a full drain.
__global__ __launch_bounds__(256) void gemm_qkv(const u16* __restrict__ A,
                                                const u16* __restrict__ Bm,
                                                const float* __restrict__ bias,
                                                u16* __restrict__ q16,
                                                u16* __restrict__ kf,
                                                u16* __restrict__ vf) {
  __shared__ u16 SH[24576];            // 49152 B: As 3x8KB | Bs 3x8KB
  u16* Asb = SH;
  u16* Bsb = SH + 12288;
  const int tid = threadIdx.x;
  const int w = tid >> 6, l = tid & 63;
  const int wr = w >> 1, wc = w & 1;
  const int l15 = l & 15, lg = l >> 4;
  const int nx = gridDim.x;
  int bid = blockIdx.y * nx + blockIdx.x;
  int cpx = (nx * gridDim.y) >> 3;
  int swz = (bid & 7) * cpx + (bid >> 3);
  int bx = swz % nx, by = swz / nx;
  const u16* Ab = A + (size_t)(bx * 128) * C_;
  const u16* Bb = Bm + (size_t)(by * 128) * C_;
  const int arow = tid >> 2;
  const int ac8 = (((tid & 3) ^ ((tid >> 3) & 3)) * 8);  // inverse-swz source chunk
  const int lgs = lg ^ ((l15 >> 1) & 3);                 // swizzled read chunk
  f32x4 acc[4][4];
#pragma unroll
  for (int m = 0; m < 4; ++m)
#pragma unroll
    for (int n = 0; n < 4; ++n) acc[m][n] = (f32x4){0.f, 0.f, 0.f, 0.f};

  auto STAGE = [&](int t, int bb) {
    const int kt = t * 32;
#pragma unroll
    for (int i = 0; i < 2; ++i) {
      gload_lds16(Ab + (size_t)(i * 64 + arow) * C_ + kt + ac8,
                  (char*)Asb + bb * 8192 + (i * 64 + w * 16) * 64);
      gload_lds16(Bb + (size_t)(i * 64 + arow) * C_ + kt + ac8,
                  (char*)Bsb + bb * 8192 + (i * 64 + w * 16) * 64);
    }
  };

  STAGE(0, 0);
  STAGE(1, 1);
  asm volatile("s_waitcnt vmcnt(4)" ::: "memory");   // tile 0 landed; tile 1 in flight
  __builtin_amdgcn_sched_barrier(0);
  __builtin_amdgcn_s_barrier();
  __builtin_amdgcn_sched_barrier(0);

  for (int t = 0; t < 32; ++t) {
    if (t + 2 < 32) STAGE(t + 2, (t + 2) % 3);
    const char* Ap = (const char*)Asb + (t % 3) * 8192;
    const char* Bp = (const char*)Bsb + (t % 3) * 8192;
    half8 af[4], bf[4];
#pragma unroll
    for (int m = 0; m < 4; ++m)
      af[m] = __builtin_bit_cast(half8, *(const short8*)(Ap +
                  (wr * 64 + m * 16 + l15) * 64 + lgs * 16));
#pragma unroll
    for (int n = 0; n < 4; ++n)
      bf[n] = __builtin_bit_cast(half8, *(const short8*)(Bp +
                  (wc * 64 + n * 16 + l15) * 64 + lgs * 16));
#pragma unroll
    for (int m = 0; m < 4; ++m)
#pragma unroll
      for (int n = 0; n < 4; ++n)
        acc[m][n] = __builtin_amdgcn_mfma_f32_16x16x32_f16(af[m], bf[n], acc[m][n], 0, 0, 0);
    if (t + 1 < 32) {
      if (t + 2 < 32)
        asm volatile("s_waitcnt vmcnt(4)" ::: "memory");  // t+1 landed; t+2 in flight
      else
        asm volatile("s_waitcnt vmcnt(0)" ::: "memory");  // drain last tile
      __builtin_amdgcn_sched_barrier(0);
      __builtin_amdgcn_s_barrier();
      __builtin_amdgcn_sched_barrier(0);
    }
  }

  // ---- epilogue write phase: tile (+bias, f16) -> SH[key][col] (pad 136) ----
  __syncthreads();   // full drain; staging LDS is dead, SH aliases it
#pragma unroll
  for (int n = 0; n < 4; ++n) {
    int colL = wc * 64 + n * 16 + l15;
    float bval = bias[by * 128 + colL];
#pragma unroll
    for (int m = 0; m < 4; ++m)
#pragma unroll
      for (int i = 0; i < 4; ++i)
        SH[(wr * 64 + m * 16 + lg * 4 + i) * 136 + colL] = f2h(acc[m][n][i] + bval);
  }
  __syncthreads();

  // ---- epilogue scatter phase: 8 coalesced 16B stores per lane ----
  if (by < 8) {
    const int c8 = l & 15;
    const int rb = w * 32 + (l >> 4);
    u16* qb = q16 + (size_t)(bx * 128) * C_ + by * 128;
#pragma unroll
    for (int j = 0; j < 8; ++j) {
      int r = rb + j * 4;
      *(short8*)(qb + (size_t)r * C_ + c8 * 8) = *(const short8*)&SH[r * 136 + c8 * 8];
    }
  } else if (by < 16) {
    const int h_loc = w & 1, t_loc = w >> 1;
    const int l31k = l & 31, hi2 = l >> 5;
    const int bh = (bx >> 4) * 16 + (by - 8) * 2 + h_loc;
    const int t = (bx & 15) * 2 + t_loc;
    u16* kb = kf + (size_t)(bh * 32 + t) * 4096;
#pragma unroll
    for (int j = 0; j < 8; ++j) {
      int kh = j >> 2, df = j & 3;
      int keyL = t_loc * 64 + kh * 32 + l31k;
      int colL = h_loc * 64 + (df * 2 + hi2) * 8;
      *(short8*)(kb + (j * 64 + l) * 8) = *(const short8*)&SH[keyL * 136 + colL];
    }
  } else {
    const int h_loc = w & 1, t_loc = w >> 1;
    const int l31v = l & 31, hi2 = l >> 5;
    const int bh = (bx >> 4) * 16 + (by - 16) * 2 + h_loc;
    const int t = (bx & 15) * 2 + t_loc;
    u16* vb = vf + (size_t)(bh * 32 + t) * 4096;
#pragma unroll
    for (int j = 0; j < 8; ++j) {
      int vh = j >> 2, kc = j & 3;
      int colL = h_loc * 64 + vh * 32 + l31v;
      short8 o;
#pragma unroll
      for (int jj = 0; jj < 8; ++jj) {
        int keyL = t_loc * 64 + kc * 16 + (jj & 3) + 8 * (jj >> 2) + 4 * hi2;
        o[jj] = (short)SH[keyL * 136 + colL];
      }
      *(short8*)(vb + (j * 64 + l) * 8) = o;
    }
  }
}

// Output-projection GEMM: C[M][1024] = att * wp16^T + b (f32 out).
// Same 3-buffer counted-vmcnt pipeline as gemm_qkv.
__global__ __launch_bounds__(256) void gemm_bt(const u16* __restrict__ A,
                                               const u16* __restrict__ Bm,
                                               const float* __restrict__ bias,
                                               float* __restrict__ outp, int Nout) {
  __shared__ u16 As[3][128 * 32];
  __shared__ u16 Bs[3][128 * 32];
  const int tid = threadIdx.x;
  const int w = tid >> 6, l = tid & 63;
  const int wr = w >> 1, wc = w & 1;
  const int l15 = l & 15, lg = l >> 4;
  const int nx = gridDim.x;
  int bid = blockIdx.y * nx + blockIdx.x;
  int cpx = (nx * gridDim.y) >> 3;
  int swz = (bid & 7) * cpx + (bid >> 3);
  int bx = swz % nx, by = swz / nx;
  const u16* Ab = A + (size_t)(bx * 128) * C_;
  const u16* Bb = Bm + (size_t)(by * 128) * C_;
  const int arow = tid >> 2;
  const int ac8 = (((tid & 3) ^ ((tid >> 3) & 3)) * 8);
  const int lgs = lg ^ ((l15 >> 1) & 3);
  f32x4 acc[4][4];
#pragma unroll
  for (int m = 0; m < 4; ++m)
#pragma unroll
    for (int n = 0; n < 4; ++n) acc[m][n] = (f32x4){0.f, 0.f, 0.f, 0.f};

  auto STAGE = [&](int t, int bb) {
    const int kt = t * 32;
#pragma unroll
    for (int i = 0; i < 2; ++i) {
      gload_lds16(Ab + (size_t)(i * 64 + arow) * C_ + kt + ac8,
                  (char*)As[bb] + (i * 64 + w * 16) * 64);
      gload_lds16(Bb + (size_t)(i * 64 + arow) * C_ + kt + ac8,
                  (char*)Bs[bb] + (i * 64 + w * 16) * 64);
    }
  };

  STAGE(0, 0);
  STAGE(1, 1);
  asm volatile("s_waitcnt vmcnt(4)" ::: "memory");
  __builtin_amdgcn_sched_barrier(0);
  __builtin_amdgcn_s_barrier();
  __builtin_amdgcn_sched_barrier(0);

  for (int t = 0; t < 32; ++t) {
    if (t + 2 < 32) STAGE(t + 2, (t + 2) % 3);
    const char* Ap = (const char*)As[t % 3];
    const char* Bp = (const char*)Bs[t % 3];
    half8 af[4], bf[4];
#pragma unroll
    for (int m = 0; m < 4; ++m)
      af[m] = __builtin_bit_cast(half8, *(const short8*)(Ap +
                  (wr * 64 + m * 16 + l15) * 64 + lgs * 16));
#pragma unroll
    for (int n = 0; n < 4; ++n)
      bf[n] = __builtin_bit_cast(half8, *(const short8*)(Bp +
                  (wc * 64 + n * 16 + l15) * 64 + lgs * 16));
#pragma unroll
    for (int m = 0; m < 4; ++m)
#pragma unroll
      for (int n = 0; n < 4; ++n)
        acc[m][n] = __builtin_amdgcn_mfma_f32_16x16x32_f16(af[m], bf[n], acc[m][n], 0, 0, 0);
    if (t + 1 < 32) {
      if (t + 2 < 32)
        asm volatile("s_waitcnt vmcnt(4)" ::: "memory");
      else
        asm volatile("s_waitcnt vmcnt(0)" ::: "memory");
      __builtin_amdgcn_sched_barrier(0);
      __builtin_amdgcn_s_barrier();
      __builtin_amdgcn_sched_barrier(0);
    }
  }

#pragma unroll
  for (int m = 0; m < 4; ++m)
#pragma unroll
    for (int n = 0; n < 4; ++n) {
      int col = by * 128 + wc * 64 + n * 16 + l15;
      float bval = bias[col];
#pragma unroll
      for (int i = 0; i < 4; ++i) {
        int row = bx * 128 + wr * 64 + m * 16 + lg * 4 + i;
        outp[(size_t)row * Nout + col] = acc[m][n][i] + bval;
      }
    }
}

// Flash attention (fp16, static-max softmax, NO LDS / NO barriers).
// Round-11 validated form: 64 q-rows per wave (two q-sets A/B share every
// K/V fragment read), full 32-tile KV walk. Q from compact q16 (stride 1024).
// Block = 4 independent waves x 64 q = 256 q. Grid (8, 64) XCD-swizzled.
__global__ __launch_bounds__(256, 2) void attn_fused(const u16* __restrict__ q16,
                                                     const u16* __restrict__ kf,
                                                     const u16* __restrict__ vf,
                                                     u16* __restrict__ att) {
  const int tid = threadIdx.x;
  const int w = tid >> 6, l = tid & 63;
  const int l31 = l & 31, hi = l >> 5;
  int bid = blockIdx.y * gridDim.x + blockIdx.x;
  int swz = (bid & 7) * 64 + (bid >> 3);       // 512 blocks -> 64 per XCD
  const int qt = swz & 7, bh = swz >> 3;
  const int b = bh >> 4, h = bh & 15;
  const int qb = qt * 256 + w * 64;            // wave covers q [qb, qb+64)

  const float sc2 = 0.125f * 1.4426950408889634f;  // scale * log2(e)
  half8 qfA[4], qfB[4];
  {
    const _Float16 sch = (_Float16)sc2;
    const u16* qrowA = q16 + (size_t)(b * N_ + qb + l31) * C_ + h * D_ + hi * 8;
    const u16* qrowB = qrowA + (size_t)32 * C_;
#pragma unroll
    for (int df = 0; df < 4; ++df) {
      half8 qa = __builtin_bit_cast(half8, *(const short8*)(qrowA + df * 16));
      half8 qc = __builtin_bit_cast(half8, *(const short8*)(qrowB + df * 16));
#pragma unroll
      for (int j = 0; j < 8; ++j) { qa[j] *= sch; qc[j] *= sch; }
      qfA[df] = qa;
      qfB[df] = qc;
    }
  }

  f32x16 aA0, aA1, aB0, aB1;  // O^T tiles per set (d 0..31 / 32..63), col q = l31
#pragma unroll
  for (int j = 0; j < 16; ++j) { aA0[j] = 0.f; aA1[j] = 0.f; aB0[j] = 0.f; aB1[j] = 0.f; }
  float lrowA = 0.f, lrowB = 0.f;

  const u16* kp = kf + (size_t)bh * 32 * 4096;
  const u16* vp = vf + (size_t)bh * 32 * 4096;
  const int loff = l * 8;

#define MKPF(SV, J0, OUT)                                                      \
  {                                                                            \
    u32x4 wq = {pk2h(SV[J0 + 0], SV[J0 + 1]), pk2h(SV[J0 + 2], SV[J0 + 3]),   \
                pk2h(SV[J0 + 4], SV[J0 + 5]), pk2h(SV[J0 + 6], SV[J0 + 7])};   \
    OUT = __builtin_bit_cast(half8, wq);                                       \
  }

  for (int t = 0; t < 32; ++t) {
    const u16* kt = kp + t * 4096;
    const u16* vt = vp + t * 4096;

    half8 kfr[2][4];
#pragma unroll
    for (int kh = 0; kh < 2; ++kh)
#pragma unroll
      for (int df = 0; df < 4; ++df)
        kfr[kh][df] = __builtin_bit_cast(half8,
            *(const short8*)(kt + ((kh * 4 + df) * 64) * 8 + loff));

    // ---- set A ----
    f32x16 sA0, sA1;
#pragma unroll
    for (int j = 0; j < 16; ++j) { sA0[j] = 0.f; sA1[j] = 0.f; }
    __builtin_amdgcn_s_setprio(1);
#pragma unroll
    for (int df = 0; df < 4; ++df) {
      sA0 = __builtin_amdgcn_mfma_f32_32x32x16_f16(kfr[0][df], qfA[df], sA0, 0, 0, 0);
      sA1 = __builtin_amdgcn_mfma_f32_32x32x16_f16(kfr[1][df], qfA[df], sA1, 0, 0, 0);
    }
    __builtin_amdgcn_s_setprio(0);
    float suA[4] = {0.f, 0.f, 0.f, 0.f};
#pragma unroll
    for (int j = 0; j < 16; ++j) {
      sA0[j] = __builtin_amdgcn_exp2f(sA0[j]);
      suA[j & 3] += sA0[j];
    }
#pragma unroll
    for (int j = 0; j < 16; ++j) {
      sA1[j] = __builtin_amdgcn_exp2f(sA1[j]);
      suA[j & 3] += sA1[j];
    }
    lrowA += (suA[0] + suA[1]) + (suA[2] + suA[3]);
    half8 pfA0, pfA1, pfA2, pfA3;
    MKPF(sA0, 0, pfA0)
    MKPF(sA0, 8, pfA1)
    MKPF(sA1, 0, pfA2)
    MKPF(sA1, 8, pfA3)

    // ---- set B ----
    f32x16 sB0, sB1;
#pragma unroll
    for (int j = 0; j < 16; ++j) { sB0[j] = 0.f; sB1[j] = 0.f; }
    __builtin_amdgcn_s_setprio(1);
#pragma unroll
    for (int df = 0; df < 4; ++df) {
      sB0 = __builtin_amdgcn_mfma_f32_32x32x16_f16(kfr[0][df], qfB[df], sB0, 0, 0, 0);
      sB1 = __builtin_amdgcn_mfma_f32_32x32x16_f16(kfr[1][df], qfB[df], sB1, 0, 0, 0);
    }
    __builtin_amdgcn_s_setprio(0);

    half8 vfr[2][4];
#pragma unroll
    for (int vh = 0; vh < 2; ++vh)
#pragma unroll
      for (int kc = 0; kc < 4; ++kc)
        vfr[vh][kc] = __builtin_bit_cast(half8,
            *(const short8*)(vt + ((vh * 4 + kc) * 64) * 8 + loff));

    float suB[4] = {0.f, 0.f, 0.f, 0.f};
#pragma unroll
    for (int j = 0; j < 16; ++j) {
      sB0[j] = __builtin_amdgcn_exp2f(sB0[j]);
      suB[j & 3] += sB0[j];
    }
#pragma unroll
    for (int j = 0; j < 16; ++j) {
      sB1[j] = __builtin_amdgcn_exp2f(sB1[j]);
      suB[j & 3] += sB1[j];
    }
    lrowB += (suB[0] + suB[1]) + (suB[2] + suB[3]);
    half8 pfB0, pfB1, pfB2, pfB3;
    MKPF(sB0, 0, pfB0)
    MKPF(sB0, 8, pfB1)
    MKPF(sB1, 0, pfB2)
    MKPF(sB1, 8, pfB3)

    // ---- PV ----
    __builtin_amdgcn_s_setprio(1);
    aA0 = __builtin_amdgcn_mfma_f32_32x32x16_f16(vfr[0][0], pfA0, aA0, 0, 0, 0);
    aA1 = __builtin_amdgcn_mfma_f32_32x32x16_f16(vfr[1][0], pfA0, aA1, 0, 0, 0);
    aB0 = __builtin_amdgcn_mfma_f32_32x32x16_f16(vfr[0][0], pfB0, aB0, 0, 0, 0);
    aB1 = __builtin_amdgcn_mfma_f32_32x32x16_f16(vfr[1][0], pfB0, aB1, 0, 0, 0);
    aA0 = __builtin_amdgcn_mfma_f32_32x32x16_f16(vfr[0][1], pfA1, aA0, 0, 0, 0);
    aA1 = __builtin_amdgcn_mfma_f32_32x32x16_f16(vfr[1][1], pfA1, aA1, 0, 0, 0);
    aB0 = __builtin_amdgcn_mfma_f32_32x32x16_f16(vfr[0][1], pfB1, aB0, 0, 0, 0);
    aB1 = __builtin_amdgcn_mfma_f32_32x32x16_f16(vfr[1][1], pfB1, aB1, 0, 0, 0);
    aA0 = __builtin_amdgcn_mfma_f32_32x32x16_f16(vfr[0][2], pfA2, aA0, 0, 0, 0);
    aA1 = __builtin_amdgcn_mfma_f32_32x32x16_f16(vfr[1][2], pfA2, aA1, 0, 0, 0);
    aB0 = __builtin_amdgcn_mfma_f32_32x32x16_f16(vfr[0][2], pfB2, aB0, 0, 0, 0);
    aB1 = __builtin_amdgcn_mfma_f32_32x32x16_f16(vfr[1][2], pfB2, aB1, 0, 0, 0);
    aA0 = __builtin_amdgcn_mfma_f32_32x32x16_f16(vfr[0][3], pfA3, aA0, 0, 0, 0);
    aA1 = __builtin_amdgcn_mfma_f32_32x32x16_f16(vfr[1][3], pfA3, aA1, 0, 0, 0);
    aB0 = __builtin_amdgcn_mfma_f32_32x32x16_f16(vfr[0][3], pfB3, aB0, 0, 0, 0);
    aB1 = __builtin_amdgcn_mfma_f32_32x32x16_f16(vfr[1][3], pfB3, aB1, 0, 0, 0);
    __builtin_amdgcn_s_setprio(0);
  }
#undef MKPF

  // epilogue: att[m][C] fp16 = O^T / rowsum for both q-sets
  {
    lrowA += __shfl_xor(lrowA, 32);
    lrowB += __shfl_xor(lrowB, 32);
    float rinvA = 1.0f / lrowA;
    float rinvB = 1.0f / lrowB;
    u16* orowA = att + (size_t)(b * N_ + qb + l31) * C_ + h * D_;
    u16* orowB = orowA + (size_t)32 * C_;
#pragma unroll
    for (int dt = 0; dt < 2; ++dt) {
#pragma unroll
      for (int r2 = 0; r2 < 4; ++r2) {
        int d0 = dt * 32 + r2 * 8 + hi * 4;
        s16x4 hvA, hvB;
#pragma unroll
        for (int i = 0; i < 4; ++i) {
          float vA = (dt ? aA1[r2 * 4 + i] : aA0[r2 * 4 + i]) * rinvA;
          float vB = (dt ? aB1[r2 * 4 + i] : aB0[r2 * 4 + i]) * rinvB;
          hvA[i] = (short)f2h(vA);
          hvB[i] = (short)f2h(vB);
        }
        *(s16x4*)(orowA + d0) = hvA;
        *(s16x4*)(orowB + d0) = hvB;
      }
    }
  }
}

extern "C" void kernel_launch(void* const* d_in, const int* in_sizes, int n_in,
                              void* d_out, int out_size, void* d_ws, size_t ws_size,
                              hipStream_t stream) {
  const float* x = (const float*)d_in[0];
  const float* w_qkv = (const float*)d_in[1];
  const float* b_qkv = (const float*)d_in[2];
  const float* w_proj = (const float*)d_in[3];
  const float* b_proj = (const float*)d_in[4];

  char* ws = (char*)d_ws;
  u16* q16  = (u16*)(ws + 0);            // 8192*1024*2 = 16777216
  u16* x16  = (u16*)(ws + 16777216);     // 16777216
  u16* wq16 = (u16*)(ws + 33554432);     //  6291456
  u16* wp16 = (u16*)(ws + 39845888);     //  2097152
  u16* kf   = (u16*)(ws + 41943040);     // 16777216  (K fragments)
  u16* vf   = (u16*)(ws + 58720256);     // 16777216  (V fragments)
  u16* att  = (u16*)(ws + 75497472);     // 16777216

  f32_to_f16_all<<<6144, 256, 0, stream>>>(x, w_qkv, w_proj, x16, wq16, wp16);

  gemm_qkv<<<dim3(64, 24), 256, 0, stream>>>(x16, wq16, b_qkv, q16, kf, vf);

  attn_fused<<<dim3(8, 64), 256, 0, stream>>>(q16, kf, vf, att);

  gemm_bt<<<dim3(64, 8), 256, 0, stream>>>(att, wp16, b_proj, (float*)d_out, C_);
}

// Round 23
// 186.431 us; speedup vs baseline: 1.0580x; 1.0580x over previous
//
#include <hip/hip_runtime.h>

typedef unsigned short u16;
typedef __attribute__((ext_vector_type(8))) short short8;    // 8 x 16-bit payload
typedef __attribute__((ext_vector_type(4))) short s16x4;
typedef __attribute__((ext_vector_type(8))) _Float16 half8;  // MFMA f16 A/B frag
typedef __attribute__((ext_vector_type(4))) float f32x4;
typedef __attribute__((ext_vector_type(16))) float f32x16;
typedef __attribute__((ext_vector_type(4))) unsigned int u32x4;

#define DEVI static __device__ __forceinline__

static constexpr int B_ = 4, N_ = 2048, C_ = 1024, H_ = 16, D_ = 64;
static constexpr int M_ = B_ * N_;   // 8192
static constexpr int C3 = 3072;

DEVI u16 f2h(float f) {
  _Float16 h = (_Float16)f;          // v_cvt_f16_f32, RTN
  return __builtin_bit_cast(u16, h);
}

DEVI unsigned pk2h(float lo, float hi) {  // pack 2 f32 -> 2 f16 (lo in [15:0])
  return __builtin_bit_cast(unsigned, __builtin_amdgcn_cvt_pkrtz(lo, hi));
}

DEVI void gload_lds16(const void* g, void* lds) {
  __builtin_amdgcn_global_load_lds(
      (const __attribute__((address_space(1))) unsigned int*)g,
      (__attribute__((address_space(3))) unsigned int*)lds, 16, 0, 0);
}

// All three f32->f16 casts in one launch (1572864 = 6144*256 chunks of 8).
__global__ __launch_bounds__(256) void f32_to_f16_all(const float* __restrict__ x,
                                                      const float* __restrict__ wq,
                                                      const float* __restrict__ wp,
                                                      u16* __restrict__ x16,
                                                      u16* __restrict__ wq16,
                                                      u16* __restrict__ wp16) {
  int idx = blockIdx.x * 256 + threadIdx.x;
  const float* s;
  u16* d;
  int base;
  if (idx < 1048576) {
    s = x; d = x16; base = idx;
  } else if (idx < 1048576 + 393216) {
    s = wq; d = wq16; base = idx - 1048576;
  } else {
    s = wp; d = wp16; base = idx - 1441792;
  }
  const float* sp = s + (size_t)base * 8;
  f32x4 f0 = *(const f32x4*)sp;
  f32x4 f1 = *(const f32x4*)(sp + 4);
  short8 o;
#pragma unroll
  for (int j = 0; j < 8; ++j) o[j] = (short)f2h(j < 4 ? f0[j] : f1[j - 4]);
  *(short8*)(d + (size_t)base * 8) = o;
}

// QKV GEMM with fused fragment scatter (round-21 validated, best measured).
// K-loop = round-18 form (128x128 tile, BK=64, chunk^=(row&7) swizzle,
// linear LDS dest + inverse-permuted global source per rule 21).
// Epilogue: dump the f16 tile (+bias) into SH[key 128][col 136-padded],
// barrier, then 8 coalesced 16B stores per lane (addresses linear in lane).
//   kf chunk  (bh*32+t)*512 + (kh*4+df)*64 + (hi*32+l31)  holds
//       K[key=kh*32+l31][d=(df*2+hi)*8 ..+8]
//   vf chunk  (bh*32+t)*512 + (vh*4+kc)*64 + (hi2*32+l31v) elem jj holds
//       V[key=kc*16+(jj&3)+8*(jj>>2)+4*hi2][d=vh*32+l31v]
__global__ __launch_bounds__(256) void gemm_qkv(const u16* __restrict__ A,
                                                const u16* __restrict__ Bm,
                                                const float* __restrict__ bias,
                                                u16* __restrict__ q16,
                                                u16* __restrict__ kf,
                                                u16* __restrict__ vf) {
  __shared__ u16 SH[128 * 136];          // 34816 B; first 32 KB double as As/Bs
  u16* As = SH;                          // 128*64
  u16* Bs = SH + 128 * 64;
  const int tid = threadIdx.x;
  const int w = tid >> 6, l = tid & 63;
  const int wr = w >> 1, wc = w & 1;
  const int l15 = l & 15, lg = l >> 4;
  const int e7 = l15 & 7;
  const int nx = gridDim.x;
  int bid = blockIdx.y * nx + blockIdx.x;
  int cpx = (nx * gridDim.y) >> 3;
  int swz = (bid & 7) * cpx + (bid >> 3);
  int bx = swz % nx, by = swz / nx;
  const u16* Ab = A + (size_t)(bx * 128) * C_;
  const u16* Bb = Bm + (size_t)(by * 128) * C_;
  const int srow = tid >> 3;
  const int sgc8 = (((tid & 7) ^ ((tid >> 3) & 7)) * 8);
  const int fc0 = (lg ^ e7) << 4;
  const int fc1 = ((4 + lg) ^ e7) << 4;
  f32x4 acc[4][4];
#pragma unroll
  for (int m = 0; m < 4; ++m)
#pragma unroll
    for (int n = 0; n < 4; ++n) acc[m][n] = (f32x4){0.f, 0.f, 0.f, 0.f};

  for (int kt = 0; kt < C_; kt += 64) {
    __syncthreads();
#pragma unroll
    for (int i = 0; i < 4; ++i) {
      int r = i * 32 + srow;
      gload_lds16(Ab + (size_t)r * C_ + kt + sgc8, (char*)As + i * 4096 + w * 1024);
      gload_lds16(Bb + (size_t)r * C_ + kt + sgc8, (char*)Bs + i * 4096 + w * 1024);
    }
    __syncthreads();
#pragma unroll
    for (int kk = 0; kk < 2; ++kk) {
      const int fco = kk ? fc1 : fc0;
      half8 af[4], bf[4];
#pragma unroll
      for (int m = 0; m < 4; ++m)
        af[m] = __builtin_bit_cast(half8, *(const short8*)((const char*)As +
                    (wr * 64 + m * 16 + l15) * 128 + fco));
#pragma unroll
      for (int n = 0; n < 4; ++n)
        bf[n] = __builtin_bit_cast(half8, *(const short8*)((const char*)Bs +
                    (wc * 64 + n * 16 + l15) * 128 + fco));
#pragma unroll
      for (int m = 0; m < 4; ++m)
#pragma unroll
        for (int n = 0; n < 4; ++n)
          acc[m][n] = __builtin_amdgcn_mfma_f32_16x16x32_f16(af[m], bf[n], acc[m][n], 0, 0, 0);
    }
  }

  // ---- epilogue write phase: tile (+bias, f16) -> SH[key][col] (pad 136) ----
  __syncthreads();   // last tile's LDS reads complete before overwrite
#pragma unroll
  for (int n = 0; n < 4; ++n) {
    int colL = wc * 64 + n * 16 + l15;
    float bval = bias[by * 128 + colL];
#pragma unroll
    for (int m = 0; m < 4; ++m)
#pragma unroll
      for (int i = 0; i < 4; ++i)
        SH[(wr * 64 + m * 16 + lg * 4 + i) * 136 + colL] = f2h(acc[m][n][i] + bval);
  }
  __syncthreads();

  // ---- epilogue scatter phase: 8 coalesced 16B stores per lane ----
  if (by < 8) {
    // Q: compact [8192][1024]
    const int c8 = l & 15;
    const int rb = w * 32 + (l >> 4);
    u16* qb = q16 + (size_t)(bx * 128) * C_ + by * 128;
#pragma unroll
    for (int j = 0; j < 8; ++j) {
      int r = rb + j * 4;
      *(short8*)(qb + (size_t)r * C_ + c8 * 8) = *(const short8*)&SH[r * 136 + c8 * 8];
    }
  } else if (by < 16) {
    // K -> kf (wave = one 64-key x 64-d subtile; store addr linear in lane)
    const int h_loc = w & 1, t_loc = w >> 1;
    const int l31k = l & 31, hi2 = l >> 5;
    const int bh = (bx >> 4) * 16 + (by - 8) * 2 + h_loc;
    const int t = (bx & 15) * 2 + t_loc;
    u16* kb = kf + (size_t)(bh * 32 + t) * 4096;
#pragma unroll
    for (int j = 0; j < 8; ++j) {
      int kh = j >> 2, df = j & 3;
      int keyL = t_loc * 64 + kh * 32 + l31k;
      int colL = h_loc * 64 + (df * 2 + hi2) * 8;
      *(short8*)(kb + (j * 64 + l) * 8) = *(const short8*)&SH[keyL * 136 + colL];
    }
  } else {
    // V -> vf (register-order key permutation; gather 8 keys per chunk)
    const int h_loc = w & 1, t_loc = w >> 1;
    const int l31v = l & 31, hi2 = l >> 5;
    const int bh = (bx >> 4) * 16 + (by - 16) * 2 + h_loc;
    const int t = (bx & 15) * 2 + t_loc;
    u16* vb = vf + (size_t)(bh * 32 + t) * 4096;
#pragma unroll
    for (int j = 0; j < 8; ++j) {
      int vh = j >> 2, kc = j & 3;
      int colL = h_loc * 64 + vh * 32 + l31v;
      short8 o;
#pragma unroll
      for (int jj = 0; jj < 8; ++jj) {
        int keyL = t_loc * 64 + kc * 16 + (jj & 3) + 8 * (jj >> 2) + 4 * hi2;
        o[jj] = (short)SH[keyL * 136 + colL];
      }
      *(short8*)(vb + (j * 64 + l) * 8) = o;
    }
  }
}

// Output-projection GEMM: C[M][1024] = att * wp16^T + b (f32 out).
// Round-18 validated form (BK=64 + swizzle).
__global__ __launch_bounds__(256) void gemm_bt(const u16* __restrict__ A,
                                               const u16* __restrict__ Bm,
                                               const float* __restrict__ bias,
                                               float* __restrict__ outp, int Nout) {
  __shared__ u16 As[128 * 64];
  __shared__ u16 Bs[128 * 64];
  const int tid = threadIdx.x;
  const int w = tid >> 6, l = tid & 63;
  const int wr = w >> 1, wc = w & 1;
  const int l15 = l & 15, lg = l >> 4;
  const int e7 = l15 & 7;
  const int nx = gridDim.x;
  int bid = blockIdx.y * nx + blockIdx.x;
  int cpx = (nx * gridDim.y) >> 3;
  int swz = (bid & 7) * cpx + (bid >> 3);
  int bx = swz % nx, by = swz / nx;
  const u16* Ab = A + (size_t)(bx * 128) * C_;
  const u16* Bb = Bm + (size_t)(by * 128) * C_;
  const int srow = tid >> 3;
  const int sgc8 = (((tid & 7) ^ ((tid >> 3) & 7)) * 8);
  const int fc0 = (lg ^ e7) << 4;
  const int fc1 = ((4 + lg) ^ e7) << 4;
  f32x4 acc[4][4];
#pragma unroll
  for (int m = 0; m < 4; ++m)
#pragma unroll
    for (int n = 0; n < 4; ++n) acc[m][n] = (f32x4){0.f, 0.f, 0.f, 0.f};

  for (int kt = 0; kt < C_; kt += 64) {
    __syncthreads();
#pragma unroll
    for (int i = 0; i < 4; ++i) {
      int r = i * 32 + srow;
      gload_lds16(Ab + (size_t)r * C_ + kt + sgc8, (char*)As + i * 4096 + w * 1024);
      gload_lds16(Bb + (size_t)r * C_ + kt + sgc8, (char*)Bs + i * 4096 + w * 1024);
    }
    __syncthreads();
#pragma unroll
    for (int kk = 0; kk < 2; ++kk) {
      const int fco = kk ? fc1 : fc0;
      half8 af[4], bf[4];
#pragma unroll
      for (int m = 0; m < 4; ++m)
        af[m] = __builtin_bit_cast(half8, *(const short8*)((const char*)As +
                    (wr * 64 + m * 16 + l15) * 128 + fco));
#pragma unroll
      for (int n = 0; n < 4; ++n)
        bf[n] = __builtin_bit_cast(half8, *(const short8*)((const char*)Bs +
                    (wc * 64 + n * 16 + l15) * 128 + fco));
#pragma unroll
      for (int m = 0; m < 4; ++m)
#pragma unroll
        for (int n = 0; n < 4; ++n)
          acc[m][n] = __builtin_amdgcn_mfma_f32_16x16x32_f16(af[m], bf[n], acc[m][n], 0, 0, 0);
    }
  }
#pragma unroll
  for (int m = 0; m < 4; ++m)
#pragma unroll
    for (int n = 0; n < 4; ++n) {
      int col = by * 128 + wc * 64 + n * 16 + l15;
      float bval = bias[col];
#pragma unroll
      for (int i = 0; i < 4; ++i) {
        int row = bx * 128 + wr * 64 + m * 16 + lg * 4 + i;
        outp[(size_t)row * Nout + col] = acc[m][n][i] + bval;
      }
    }
}

// Flash attention (fp16, static-max softmax, NO LDS / NO barriers).
// Round-11 validated form: 64 q-rows per wave (two q-sets A/B share every
// K/V fragment read), full 32-tile KV walk. Q from compact q16 (stride 1024).
// Block = 4 independent waves x 64 q = 256 q. Grid (8, 64) XCD-swizzled.
__global__ __launch_bounds__(256, 2) void attn_fused(const u16* __restrict__ q16,
                                                     const u16* __restrict__ kf,
                                                     const u16* __restrict__ vf,
                                                     u16* __restrict__ att) {
  const int tid = threadIdx.x;
  const int w = tid >> 6, l = tid & 63;
  const int l31 = l & 31, hi = l >> 5;
  int bid = blockIdx.y * gridDim.x + blockIdx.x;
  int swz = (bid & 7) * 64 + (bid >> 3);       // 512 blocks -> 64 per XCD
  const int qt = swz & 7, bh = swz >> 3;
  const int b = bh >> 4, h = bh & 15;
  const int qb = qt * 256 + w * 64;            // wave covers q [qb, qb+64)

  const float sc2 = 0.125f * 1.4426950408889634f;  // scale * log2(e)
  half8 qfA[4], qfB[4];
  {
    const _Float16 sch = (_Float16)sc2;
    const u16* qrowA = q16 + (size_t)(b * N_ + qb + l31) * C_ + h * D_ + hi * 8;
    const u16* qrowB = qrowA + (size_t)32 * C_;
#pragma unroll
    for (int df = 0; df < 4; ++df) {
      half8 qa = __builtin_bit_cast(half8, *(const short8*)(qrowA + df * 16));
      half8 qc = __builtin_bit_cast(half8, *(const short8*)(qrowB + df * 16));
#pragma unroll
      for (int j = 0; j < 8; ++j) { qa[j] *= sch; qc[j] *= sch; }
      qfA[df] = qa;
      qfB[df] = qc;
    }
  }

  f32x16 aA0, aA1, aB0, aB1;  // O^T tiles per set (d 0..31 / 32..63), col q = l31
#pragma unroll
  for (int j = 0; j < 16; ++j) { aA0[j] = 0.f; aA1[j] = 0.f; aB0[j] = 0.f; aB1[j] = 0.f; }
  float lrowA = 0.f, lrowB = 0.f;

  const u16* kp = kf + (size_t)bh * 32 * 4096;
  const u16* vp = vf + (size_t)bh * 32 * 4096;
  const int loff = l * 8;

#define MKPF(SV, J0, OUT)                                                      \
  {                                                                            \
    u32x4 wq = {pk2h(SV[J0 + 0], SV[J0 + 1]), pk2h(SV[J0 + 2], SV[J0 + 3]),   \
                pk2h(SV[J0 + 4], SV[J0 + 5]), pk2h(SV[J0 + 6], SV[J0 + 7])};   \
    OUT = __builtin_bit_cast(half8, wq);                                       \
  }

  for (int t = 0; t < 32; ++t) {
    const u16* kt = kp + t * 4096;
    const u16* vt = vp + t * 4096;

    half8 kfr[2][4];
#pragma unroll
    for (int kh = 0; kh < 2; ++kh)
#pragma unroll
      for (int df = 0; df < 4; ++df)
        kfr[kh][df] = __builtin_bit_cast(half8,
            *(const short8*)(kt + ((kh * 4 + df) * 64) * 8 + loff));

    // ---- set A ----
    f32x16 sA0, sA1;
#pragma unroll
    for (int j = 0; j < 16; ++j) { sA0[j] = 0.f; sA1[j] = 0.f; }
    __builtin_amdgcn_s_setprio(1);
#pragma unroll
    for (int df = 0; df < 4; ++df) {
      sA0 = __builtin_amdgcn_mfma_f32_32x32x16_f16(kfr[0][df], qfA[df], sA0, 0, 0, 0);
      sA1 = __builtin_amdgcn_mfma_f32_32x32x16_f16(kfr[1][df], qfA[df], sA1, 0, 0, 0);
    }
    __builtin_amdgcn_s_setprio(0);
    float suA[4] = {0.f, 0.f, 0.f, 0.f};
#pragma unroll
    for (int j = 0; j < 16; ++j) {
      sA0[j] = __builtin_amdgcn_exp2f(sA0[j]);
      suA[j & 3] += sA0[j];
    }
#pragma unroll
    for (int j = 0; j < 16; ++j) {
      sA1[j] = __builtin_amdgcn_exp2f(sA1[j]);
      suA[j & 3] += sA1[j];
    }
    lrowA += (suA[0] + suA[1]) + (suA[2] + suA[3]);
    half8 pfA0, pfA1, pfA2, pfA3;
    MKPF(sA0, 0, pfA0)
    MKPF(sA0, 8, pfA1)
    MKPF(sA1, 0, pfA2)
    MKPF(sA1, 8, pfA3)

    // ---- set B ----
    f32x16 sB0, sB1;
#pragma unroll
    for (int j = 0; j < 16; ++j) { sB0[j] = 0.f; sB1[j] = 0.f; }
    __builtin_amdgcn_s_setprio(1);
#pragma unroll
    for (int df = 0; df < 4; ++df) {
      sB0 = __builtin_amdgcn_mfma_f32_32x32x16_f16(kfr[0][df], qfB[df], sB0, 0, 0, 0);
      sB1 = __builtin_amdgcn_mfma_f32_32x32x16_f16(kfr[1][df], qfB[df], sB1, 0, 0, 0);
    }
    __builtin_amdgcn_s_setprio(0);

    half8 vfr[2][4];
#pragma unroll
    for (int vh = 0; vh < 2; ++vh)
#pragma unroll
      for (int kc = 0; kc < 4; ++kc)
        vfr[vh][kc] = __builtin_bit_cast(half8,
            *(const short8*)(vt + ((vh * 4 + kc) * 64) * 8 + loff));

    float suB[4] = {0.f, 0.f, 0.f, 0.f};
#pragma unroll
    for (int j = 0; j < 16; ++j) {
      sB0[j] = __builtin_amdgcn_exp2f(sB0[j]);
      suB[j & 3] += sB0[j];
    }
#pragma unroll
    for (int j = 0; j < 16; ++j) {
      sB1[j] = __builtin_amdgcn_exp2f(sB1[j]);
      suB[j & 3] += sB1[j];
    }
    lrowB += (suB[0] + suB[1]) + (suB[2] + suB[3]);
    half8 pfB0, pfB1, pfB2, pfB3;
    MKPF(sB0, 0, pfB0)
    MKPF(sB0, 8, pfB1)
    MKPF(sB1, 0, pfB2)
    MKPF(sB1, 8, pfB3)

    // ---- PV ----
    __builtin_amdgcn_s_setprio(1);
    aA0 = __builtin_amdgcn_mfma_f32_32x32x16_f16(vfr[0][0], pfA0, aA0, 0, 0, 0);
    aA1 = __builtin_amdgcn_mfma_f32_32x32x16_f16(vfr[1][0], pfA0, aA1, 0, 0, 0);
    aB0 = __builtin_amdgcn_mfma_f32_32x32x16_f16(vfr[0][0], pfB0, aB0, 0, 0, 0);
    aB1 = __builtin_amdgcn_mfma_f32_32x32x16_f16(vfr[1][0], pfB0, aB1, 0, 0, 0);
    aA0 = __builtin_amdgcn_mfma_f32_32x32x16_f16(vfr[0][1], pfA1, aA0, 0, 0, 0);
    aA1 = __builtin_amdgcn_mfma_f32_32x32x16_f16(vfr[1][1], pfA1, aA1, 0, 0, 0);
    aB0 = __builtin_amdgcn_mfma_f32_32x32x16_f16(vfr[0][1], pfB1, aB0, 0, 0, 0);
    aB1 = __builtin_amdgcn_mfma_f32_32x32x16_f16(vfr[1][1], pfB1, aB1, 0, 0, 0);
    aA0 = __builtin_amdgcn_mfma_f32_32x32x16_f16(vfr[0][2], pfA2, aA0, 0, 0, 0);
    aA1 = __builtin_amdgcn_mfma_f32_32x32x16_f16(vfr[1][2], pfA2, aA1, 0, 0, 0);
    aB0 = __builtin_amdgcn_mfma_f32_32x32x16_f16(vfr[0][2], pfB2, aB0, 0, 0, 0);
    aB1 = __builtin_amdgcn_mfma_f32_32x32x16_f16(vfr[1][2], pfB2, aB1, 0, 0, 0);
    aA0 = __builtin_amdgcn_mfma_f32_32x32x16_f16(vfr[0][3], pfA3, aA0, 0, 0, 0);
    aA1 = __builtin_amdgcn_mfma_f32_32x32x16_f16(vfr[1][3], pfA3, aA1, 0, 0, 0);
    aB0 = __builtin_amdgcn_mfma_f32_32x32x16_f16(vfr[0][3], pfB3, aB0, 0, 0, 0);
    aB1 = __builtin_amdgcn_mfma_f32_32x32x16_f16(vfr[1][3], pfB3, aB1, 0, 0, 0);
    __builtin_amdgcn_s_setprio(0);
  }
#undef MKPF

  // epilogue: att[m][C] fp16 = O^T / rowsum for both q-sets
  {
    lrowA += __shfl_xor(lrowA, 32);
    lrowB += __shfl_xor(lrowB, 32);
    float rinvA = 1.0f / lrowA;
    float rinvB = 1.0f / lrowB;
    u16* orowA = att + (size_t)(b * N_ + qb + l31) * C_ + h * D_;
    u16* orowB = orowA + (size_t)32 * C_;
#pragma unroll
    for (int dt = 0; dt < 2; ++dt) {
#pragma unroll
      for (int r2 = 0; r2 < 4; ++r2) {
        int d0 = dt * 32 + r2 * 8 + hi * 4;
        s16x4 hvA, hvB;
#pragma unroll
        for (int i = 0; i < 4; ++i) {
          float vA = (dt ? aA1[r2 * 4 + i] : aA0[r2 * 4 + i]) * rinvA;
          float vB = (dt ? aB1[r2 * 4 + i] : aB0[r2 * 4 + i]) * rinvB;
          hvA[i] = (short)f2h(vA);
          hvB[i] = (short)f2h(vB);
        }
        *(s16x4*)(orowA + d0) = hvA;
        *(s16x4*)(orowB + d0) = hvB;
      }
    }
  }
}

extern "C" void kernel_launch(void* const* d_in, const int* in_sizes, int n_in,
                              void* d_out, int out_size, void* d_ws, size_t ws_size,
                              hipStream_t stream) {
  const float* x = (const float*)d_in[0];
  const float* w_qkv = (const float*)d_in[1];
  const float* b_qkv = (const float*)d_in[2];
  const float* w_proj = (const float*)d_in[3];
  const float* b_proj = (const float*)d_in[4];

  char* ws = (char*)d_ws;
  u16* q16  = (u16*)(ws + 0);            // 8192*1024*2 = 16777216
  u16* x16  = (u16*)(ws + 16777216);     // 16777216
  u16* wq16 = (u16*)(ws + 33554432);     //  6291456
  u16* wp16 = (u16*)(ws + 39845888);     //  2097152
  u16* kf   = (u16*)(ws + 41943040);     // 16777216  (K fragments)
  u16* vf   = (u16*)(ws + 58720256);     // 16777216  (V fragments)
  u16* att  = (u16*)(ws + 75497472);     // 16777216

  f32_to_f16_all<<<6144, 256, 0, stream>>>(x, w_qkv, w_proj, x16, wq16, wp16);

  gemm_qkv<<<dim3(64, 24), 256, 0, stream>>>(x16, wq16, b_qkv, q16, kf, vf);

  attn_fused<<<dim3(8, 64), 256, 0, stream>>>(q16, kf, vf, att);

  gemm_bt<<<dim3(64, 8), 256, 0, stream>>>(att, wp16, b_proj, (float*)d_out, C_);
}